// Round 3
// baseline (27324.835 us; speedup 1.0000x reference)
//
#include <hip/hip_runtime.h>
#include <math.h>

#define NWG 256
#define TPB 512
#define AGT __HIP_MEMORY_SCOPE_AGENT

// ---- sizes ----
static constexpr int Bb = 32, Dd = 512, Tt = 32, Vv = 32000;
static constexpr int BD = Bb * Dd;                       // 16384
static constexpr float SCALE_INV = 0.04419417382415922f; // 1/sqrt(512)

// ---- ws layout (float offsets). Sync region = first 16 KB. ----
static constexpr size_t OFF_H0 = 4096;
static constexpr size_t OFF_H1 = OFF_H0 + 2 * (size_t)BD;
static constexpr size_t OFF_P  = OFF_H1 + 2 * (size_t)BD;             // [32][32][2048]
static constexpr size_t OFF_HL = OFF_P + (size_t)Tt * Bb * 2048;      // [32][32][512]
static constexpr size_t OFF_HD = OFF_HL + (size_t)Tt * BD;
static constexpr size_t OFF_OF = OFF_HD + BD;                          // [32][32][512]
static constexpr size_t OFF_CV = OFF_OF + (size_t)Tt * BD;             // [32][256]
static constexpr size_t OFF_CI = OFF_CV + 32 * 256;
static constexpr size_t OFF_ET = OFF_CI + 32 * 256;                    // [512][32000]

// ---- LDS region offsets (floats) ----
static constexpr int L_W    = 0;       // 24 x 576 = 13824 weight rows
static constexpr int L_SC   = 13824;   // 512
static constexpr int L_RB   = 14336;   // 1024
static constexpr int L_IB   = 15360;   // 512
static constexpr int L_RED  = 15872;   // 16
// BIG-only:
static constexpr int L_HID  = 15888;   // 512*16 = 8192
static constexpr int L_GV   = 24080;   // 128
static constexpr int L_GI   = 24208;   // 128
static constexpr int L_TOK  = 24336;   // 32
static constexpr int BIG_FLOATS = 24368;
static constexpr size_t BIG_BYTES = (size_t)BIG_FLOATS * 4;

__device__ __forceinline__ float sigm(float x) { return 1.0f / (1.0f + expf(-x)); }

// ---- IC-coherent (sc1) access: relaxed agent-scope atomics (bypass L2, no inv/wb) ----
__device__ __forceinline__ float ldcv(const float* p) {
  unsigned u = __hip_atomic_load((const unsigned*)p, __ATOMIC_RELAXED, AGT);
  return __builtin_bit_cast(float, u);
}
__device__ __forceinline__ void stcv(float* p, float v) {
  __hip_atomic_store((unsigned*)p, __builtin_bit_cast(unsigned, v), __ATOMIC_RELAXED, AGT);
}
__device__ __forceinline__ float2 ldcv2(const float* p) {
  unsigned long long u = __hip_atomic_load((const unsigned long long*)p, __ATOMIC_RELAXED, AGT);
  return __builtin_bit_cast(float2, u);
}
__device__ __forceinline__ int ldcvi(const int* p) {
  return (int)__hip_atomic_load((const unsigned*)p, __ATOMIC_RELAXED, AGT);
}
__device__ __forceinline__ void stcvi(int* p, int v) {
  __hip_atomic_store((unsigned*)p, (unsigned)v, __ATOMIC_RELAXED, AGT);
}

__device__ __forceinline__ float wredsum(float v) {
#pragma unroll
  for (int off = 32; off > 0; off >>= 1) v += __shfl_xor(v, off, 64);
  return v;
}

// ---- fence-free 2-level grid barrier, spread release flags ----
// arrival ctr for group g at dword g*64 (256B apart); root at 1024;
// release flag for group g at 2048 + g*64. Poll interval ~s_sleep(8).
__device__ __forceinline__ void gbar(unsigned* sb, unsigned& lg) {
  const unsigned tgt = lg + 1u;
  asm volatile("s_waitcnt vmcnt(0)" ::: "memory");
  __syncthreads();
  if (threadIdx.x == 0) {
    const int g = (int)blockIdx.x >> 5;
    unsigned a = __hip_atomic_fetch_add(&sb[g * 64], 1u, __ATOMIC_RELAXED, AGT);
    if (a == 31u) {
      __hip_atomic_store(&sb[g * 64], 0u, __ATOMIC_RELAXED, AGT);
      unsigned r = __hip_atomic_fetch_add(&sb[1024], 1u, __ATOMIC_RELAXED, AGT);
      if (r == 7u) {
        __hip_atomic_store(&sb[1024], 0u, __ATOMIC_RELAXED, AGT);
#pragma unroll
        for (int gg = 0; gg < 8; ++gg)
          __hip_atomic_store(&sb[2048 + gg * 64], tgt, __ATOMIC_RELAXED, AGT);
      }
    }
    while (__hip_atomic_load(&sb[2048 + g * 64], __ATOMIC_RELAXED, AGT) < tgt)
      __builtin_amdgcn_s_sleep(8);
  }
  lg = tgt;
  __syncthreads();
}

__device__ __forceinline__ float blockMax(float v, float* red, int tid) {
#pragma unroll
  for (int off = 32; off > 0; off >>= 1) v = fmaxf(v, __shfl_xor(v, off, 64));
  if ((tid & 63) == 0) red[tid >> 6] = v;
  __syncthreads();
  float m = red[0];
#pragma unroll
  for (int i = 1; i < 8; ++i) m = fmaxf(m, red[i]);
  __syncthreads();
  return m;
}

__device__ __forceinline__ float blockSum(float v, float* red, int tid) {
  v = wredsum(v);
  if ((tid & 63) == 0) red[tid >> 6] = v;
  __syncthreads();
  float s = 0.f;
#pragma unroll
  for (int i = 0; i < 8; ++i) s += red[i];
  __syncthreads();
  return s;
}

// ---- stage this WG's 24 weight rows into LDS (slant-packed: chunk kc at kc*36) ----
__device__ void stageW(int wg, int tid, const float* __restrict__ Wih,
                       const float* __restrict__ Whh, float* __restrict__ SMW) {
  for (int e = tid; e < 3 * 8 * 512; e += TPB) {
    const int k = e & 511, jl = (e >> 9) & 7, m = e >> 12;
    const int q = jl >> 1, dl = jl & 1;
    const int j = q * 512 + wg * 2 + dl;
    const float* srcp = (m == 0) ? (Whh + (size_t)j * 512)
                     : (m == 1) ? (Wih + (size_t)2048 * 512 + (size_t)j * 512)
                                : (Whh + (size_t)2048 * 512 + (size_t)j * 512);
    SMW[(m * 8 + jl) * 576 + (k >> 5) * 36 + (k & 31)] = srcp[k];
  }
  __syncthreads();
}

// ---- WG-private transpose: WG wg owns ET column panel [wg*128, wg*128+128) ----
__device__ void transposeET(int wg, int tid, const float* __restrict__ Etrg,
                            float* __restrict__ ETw, float* __restrict__ SM) {
  if (wg < 250) {
    for (int tile = 0; tile < 8; ++tile) {
      const int tv = tile >> 2, tk = tile & 3;
      __syncthreads();
      for (int e = tid; e < 64 * 128; e += TPB) {
        const int vl = e >> 7, kl = e & 127;
        SM[vl * 129 + kl] = Etrg[(size_t)(wg * 128 + tv * 64 + vl) * 512 + tk * 128 + kl];
      }
      __syncthreads();
      for (int e = tid; e < 64 * 128; e += TPB) {
        const int kl = e >> 6, vl = e & 63;
        ETw[(size_t)(tk * 128 + kl) * 32000 + wg * 128 + tv * 64 + vl] = SM[vl * 129 + kl];
      }
    }
    __syncthreads();
  }
}

// ---- merged LSTM phase: A = L0(pos p), B = L1(pos p-1). tid = b*16 + kc. ----
__device__ __forceinline__ void phaseAB(
    int wg, int tid, bool doA, bool doB,
    const float* __restrict__ H0r, float* __restrict__ H0w,
    const float* __restrict__ H1r, float* __restrict__ H1w,
    float* __restrict__ HlP, const float* __restrict__ Pp,
    const float* __restrict__ bs1,
    const float* __restrict__ SMW, float& c0, float& c1)
{
  const int b = tid >> 4, kc = tid & 15;
  float4 h0q[8], h1q[8];
  const float* hp0 = H0r + b * 512 + kc * 32;
#pragma unroll
  for (int i = 0; i < 8; ++i)
    asm volatile("global_load_dwordx4 %0, %1, off offset:%c2 sc1"
                 : "=v"(h0q[i]) : "v"(hp0), "i"(i * 16));
  if (doB) {
    const float* hp1 = H1r + b * 512 + kc * 32;
#pragma unroll
    for (int i = 0; i < 8; ++i)
      asm volatile("global_load_dwordx4 %0, %1, off offset:%c2 sc1"
                   : "=v"(h1q[i]) : "v"(hp1), "i"(i * 16));
  }
  asm volatile("s_waitcnt vmcnt(0)" ::: "memory");
  __builtin_amdgcn_sched_barrier(0);

  float accA[8], accB[8];
#pragma unroll
  for (int r = 0; r < 8; ++r) { accA[r] = 0.f; accB[r] = 0.f; }
  if (doA) {
#pragma unroll
    for (int r = 0; r < 8; ++r) {
      const float4* wr = (const float4*)(SMW + r * 576 + kc * 36);
#pragma unroll
      for (int iq = 0; iq < 8; ++iq) {
        float4 w = wr[iq];
        accA[r] = fmaf(w.x, h0q[iq].x, accA[r]);
        accA[r] = fmaf(w.y, h0q[iq].y, accA[r]);
        accA[r] = fmaf(w.z, h0q[iq].z, accA[r]);
        accA[r] = fmaf(w.w, h0q[iq].w, accA[r]);
      }
    }
  }
  if (doB) {
#pragma unroll
    for (int r = 0; r < 8; ++r) {       // Wih1 . H0
      const float4* wr = (const float4*)(SMW + (8 + r) * 576 + kc * 36);
#pragma unroll
      for (int iq = 0; iq < 8; ++iq) {
        float4 w = wr[iq];
        accB[r] = fmaf(w.x, h0q[iq].x, accB[r]);
        accB[r] = fmaf(w.y, h0q[iq].y, accB[r]);
        accB[r] = fmaf(w.z, h0q[iq].z, accB[r]);
        accB[r] = fmaf(w.w, h0q[iq].w, accB[r]);
      }
    }
#pragma unroll
    for (int r = 0; r < 8; ++r) {       // Whh1 . H1
      const float4* wr = (const float4*)(SMW + (16 + r) * 576 + kc * 36);
#pragma unroll
      for (int iq = 0; iq < 8; ++iq) {
        float4 w = wr[iq];
        accB[r] = fmaf(w.x, h1q[iq].x, accB[r]);
        accB[r] = fmaf(w.y, h1q[iq].y, accB[r]);
        accB[r] = fmaf(w.z, h1q[iq].z, accB[r]);
        accB[r] = fmaf(w.w, h1q[iq].w, accB[r]);
      }
    }
  }
#pragma unroll
  for (int off = 1; off < 16; off <<= 1) {   // reduce over the 16 kc lanes
    if (doA) {
#pragma unroll
      for (int r = 0; r < 8; ++r) accA[r] += __shfl_xor(accA[r], off, 64);
    }
    if (doB) {
#pragma unroll
      for (int r = 0; r < 8; ++r) accB[r] += __shfl_xor(accB[r], off, 64);
    }
  }
  if (kc < 2) {                        // lanes kc=0,1 own columns d = wg*2+kc
    const int d = (wg << 1) | kc;
    if (doA) {
      const float* pb = Pp + b * 2048 + d;
      const float gi = accA[0 + kc] + pb[0];
      const float gf = accA[2 + kc] + pb[512];
      const float gg = accA[4 + kc] + pb[1024];
      const float go = accA[6 + kc] + pb[1536];
      c0 = sigm(gf) * c0 + sigm(gi) * tanhf(gg);
      stcv(H0w + b * 512 + d, sigm(go) * tanhf(c0));
    }
    if (doB) {
      const float gi = accB[0 + kc] + bs1[0];
      const float gf = accB[2 + kc] + bs1[1];
      const float gg = accB[4 + kc] + bs1[2];
      const float go = accB[6 + kc] + bs1[3];
      c1 = sigm(gf) * c1 + sigm(gi) * tanhf(gg);
      const float hn = sigm(go) * tanhf(c1);
      stcv(H1w + b * 512 + d, hn);
      if (HlP) stcv(HlP + b * 512 + d, hn);
    }
  }
}

// ---- fused fc + attention + context + h2o for one batch row (WGs 0..31) ----
__device__ void phaseCDEF(int b, int tid, const float* __restrict__ H1c,
                          const float* __restrict__ Wfc, const float* __restrict__ bfc,
                          const int* __restrict__ src, const float* __restrict__ Esrc,
                          const float* __restrict__ Wh2o, const float* __restrict__ bh2o,
                          float* __restrict__ hD, float* sc, float* rb, int* ib, float* red)
{
  rb[tid] = ldcv(H1c + b * 512 + tid);
  ib[tid] = src[b * 512 + tid];
  __syncthreads();
  const int w = tid >> 6, lane = tid & 63;
  for (int d = w; d < 512; d += 8) {            // fc_out
    const float* wr = Wfc + (size_t)d * 512;
    float p = 0.f;
#pragma unroll
    for (int i = 0; i < 8; ++i) p = fmaf(rb[lane * 8 + i], wr[lane * 8 + i], p);
    p = wredsum(p);
    if (lane == 0) rb[512 + d] = p + bfc[d];
  }
  __syncthreads();
  for (int s = w; s < 512; s += 8) {            // scores
    const float* er = Esrc + (size_t)ib[s] * 512;
    float p = 0.f;
#pragma unroll
    for (int i = 0; i < 8; ++i) p = fmaf(rb[512 + lane * 8 + i], er[lane * 8 + i], p);
    p = wredsum(p);
    if (lane == 0) sc[s] = p * SCALE_INV;
  }
  __syncthreads();
  const float mx = blockMax(sc[tid], red, tid);
  const float e = expf(sc[tid] - mx);
  sc[tid] = e;
  const float sum = blockSum(e, red, tid);
  const float inv = 1.0f / sum;
  float acc = 0.f;
#pragma unroll 4
  for (int s = 0; s < 512; ++s) acc = fmaf(sc[s], Esrc[(size_t)ib[s] * 512 + tid], acc);
  rb[tid] = acc * inv;                          // ctx into rb[0:512]
  __syncthreads();
  for (int d = w; d < 512; d += 8) {            // h2o + relu
    const float* wr = Wh2o + (size_t)d * 1024;
    float p = 0.f;
#pragma unroll
    for (int i = 0; i < 8; ++i) p = fmaf(rb[512 + lane * 8 + i], wr[lane * 8 + i], p);
#pragma unroll
    for (int i = 0; i < 8; ++i) p = fmaf(rb[lane * 8 + i], wr[512 + lane * 8 + i], p);
    p = wredsum(p);
    if (lane == 0) stcv(hD + (size_t)b * 512 + d, fmaxf(p + bh2o[d], 0.f));
  }
}

// ---- logits + per-slot argmax candidates (pre-transposed ET panel) ----
template<int PAD>
__device__ void phaseG_ET(int wg, int tid, const float* __restrict__ hD, const float* __restrict__ ET,
                          const float* __restrict__ bout, float* __restrict__ candV,
                          int* __restrict__ candI, float* hidT, float* gv, int* gi)
{
  if (wg >= 250) return;
  const int v0 = wg * 128;
#pragma unroll 1
  for (int ph = 0; ph < 2; ++ph) {
    const int bbase = ph * 16;
    __syncthreads();
    for (int e = tid; e < 16 * 512; e += TPB) {   // hidT[k][b]
      const int b = e >> 9, k = e & 511;
      hidT[k * PAD + b] = ldcv(hD + (size_t)(bbase + b) * 512 + k);
    }
    __syncthreads();
    const int vp = tid >> 3, bh = tid & 7;
    const int v = v0 + vp * 2;
    float a00 = 0.f, a01 = 0.f, a10 = 0.f, a11 = 0.f;
    const float* ep = ET + v;
    const float* hp = hidT + bh * 2;
#pragma unroll 4
    for (int k = 0; k < 512; ++k) {
      const float2 e2 = *(const float2*)(ep + (size_t)k * 32000);
      const float2 h2 = *(const float2*)(hp + (size_t)k * PAD);
      a00 = fmaf(e2.x, h2.x, a00);
      a01 = fmaf(e2.x, h2.y, a01);
      a10 = fmaf(e2.y, h2.x, a10);
      a11 = fmaf(e2.y, h2.y, a11);
    }
    const float bo0 = bout[v], bo1 = bout[v + 1];
    a00 += bo0; a01 += bo0; a10 += bo1; a11 += bo1;
    float vA, vB; int iA, iB;
    if (a10 > a00) { vA = a10; iA = v + 1; } else { vA = a00; iA = v; }
    if (a11 > a01) { vB = a11; iB = v + 1; } else { vB = a01; iB = v; }
#pragma unroll
    for (int off = 8; off < 64; off <<= 1) {
      float ov = __shfl_xor(vA, off, 64); int oi = __shfl_xor(iA, off, 64);
      if (ov > vA || (ov == vA && oi < iA)) { vA = ov; iA = oi; }
      ov = __shfl_xor(vB, off, 64); oi = __shfl_xor(iB, off, 64);
      if (ov > vB || (ov == vB && oi < iB)) { vB = ov; iB = oi; }
    }
    if ((tid & 63) < 8) {
      const int w = tid >> 6;
      gv[(bh * 2 + 0) * 8 + w] = vA; gi[(bh * 2 + 0) * 8 + w] = iA;
      gv[(bh * 2 + 1) * 8 + w] = vB; gi[(bh * 2 + 1) * 8 + w] = iB;
    }
    __syncthreads();
    if (tid < 16) {
      float bv = -INFINITY; int bi = 0;
      for (int w2 = 0; w2 < 8; ++w2) {
        const float vv = gv[tid * 8 + w2]; const int ii = gi[tid * 8 + w2];
        if (vv > bv || (vv == bv && ii < bi)) { bv = vv; bi = ii; }
      }
      stcv(candV + (size_t)(bbase + tid) * 256 + wg, bv);
      stcvi(candI + (bbase + tid) * 256 + wg, bi);
    }
  }
}

// ---- fallback logits (row-major E), wave-per-v ----
__device__ void phaseG_noET(int wg, int tid, const float* __restrict__ hD,
                            const float* __restrict__ Etrg, const float* __restrict__ bout,
                            float* __restrict__ candV, int* __restrict__ candI,
                            float* rb, float* gv, int* gi)
{
  const int b = wg >> 3, vb = wg & 7;
  rb[tid] = ldcv(hD + (size_t)b * 512 + tid);
  __syncthreads();
  const int w = tid >> 6, lane = tid & 63;
  float bv = -INFINITY; int bi = 0;
  for (int v = vb * 4000 + w; v < (vb + 1) * 4000; v += 8) {
    const float* er = Etrg + (size_t)v * 512;
    float p = 0.f;
#pragma unroll
    for (int i = 0; i < 8; ++i) p = fmaf(rb[lane * 8 + i], er[lane * 8 + i], p);
    p = wredsum(p);
    p += bout[v];
    if (p > bv || (p == bv && v < bi)) { bv = p; bi = v; }
  }
  if (lane == 0) { gv[w] = bv; gi[w] = bi; }
  __syncthreads();
  if (tid == 0) {
    float fv = -INFINITY; int fi = 0;
    for (int w2 = 0; w2 < 8; ++w2)
      if (gv[w2] > fv || (gv[w2] == fv && gi[w2] < fi)) { fv = gv[w2]; fi = gi[w2]; }
    stcv(candV + (size_t)b * 256 + vb, fv);
    stcvi(candI + b * 256 + vb, fi);
  }
}

// ---- token argmax finalize + P[t+1] projection ----
__device__ void phaseHP(int wg, int tid, int t, bool useET,
                        const float* __restrict__ candV, const int* __restrict__ candI,
                        const float* __restrict__ Etrg, const float* __restrict__ Wih,
                        const float* __restrict__ bih, const float* __restrict__ bhh,
                        float* __restrict__ P, float* __restrict__ out, int* tokL)
{
  const int nslot = useET ? 250 : 8;
  {
    const int b = tid >> 4, sl = tid & 15;
    float bv = -INFINITY; int bi = 0x7fffffff;
    for (int s = sl; s < nslot; s += 16) {
      const float vv = ldcv(candV + (size_t)b * 256 + s);
      const int ii = ldcvi(candI + b * 256 + s);
      if (vv > bv || (vv == bv && ii < bi)) { bv = vv; bi = ii; }
    }
#pragma unroll
    for (int off = 1; off < 16; off <<= 1) {
      const float ov = __shfl_xor(bv, off, 64); const int oi = __shfl_xor(bi, off, 64);
      if (ov > bv || (ov == bv && oi < bi)) { bv = ov; bi = oi; }
    }
    if (sl == 0) {
      tokL[b] = bi;
      if (wg == 0) out[b * 32 + t] = (float)bi;   // tokens[:,1:][b][t]
    }
  }
  __syncthreads();
  if (t < 31) {
    const int w = tid >> 6, lane = tid & 63;
    const int q = w >> 1, dl = w & 1;
    const int j = q * 512 + wg * 2 + dl;
    const float* wr = Wih + (size_t)j * 512;
    const float bsum = bih[j] + bhh[j];
    for (int b = 0; b < 32; ++b) {
      const float* er = Etrg + (size_t)tokL[b] * 512;
      float p = 0.f;
#pragma unroll
      for (int i = 0; i < 8; ++i) p = fmaf(er[lane * 8 + i], wr[lane * 8 + i], p);
      p = wredsum(p);
      if (lane == 0) P[((size_t)(t + 1) * 32 + b) * 2048 + j] = p + bsum;
    }
  }
  __syncthreads();
}

// ---- outfc[p][b][:] = Hlast[p][b] @ Wfc^T + bfc ----
__device__ void phaseX(int wg, int tid, const float* __restrict__ Hl, const float* __restrict__ Wfc,
                       const float* __restrict__ bfc, float* __restrict__ oF)
{
  const int p = wg >> 3, bq = wg & 7;
  const int w = tid >> 6, lane = tid & 63;
  for (int u = w; u < 2048; u += 8) {
    const int bb = u >> 9, d = u & 511;
    const int b = bq * 4 + bb;
    const float* hr = Hl + ((size_t)p * 32 + b) * 512;
    const float* wr = Wfc + (size_t)d * 512;
    float acc = 0.f;
#pragma unroll
    for (int ii = 0; ii < 4; ++ii) {
      const float2 hv = ldcv2(hr + lane * 8 + 2 * ii);
      acc = fmaf(hv.x, wr[lane * 8 + 2 * ii], acc);
      acc = fmaf(hv.y, wr[lane * 8 + 2 * ii + 1], acc);
    }
    acc = wredsum(acc);
    if (lane == 0) stcv(oF + ((size_t)p * 32 + b) * 512 + d, acc + bfc[d]);
  }
}

// ---- final attn rows: softmax_s(outfc[p][b] . src_e[b][s] / sqrt(D)) ----
__device__ void phaseY(int wg, int tid, const float* __restrict__ oF, const int* __restrict__ src,
                       const float* __restrict__ Esrc, float* __restrict__ out,
                       float* sc, float* rb, int* ib, float* red)
{
  for (int r = 0; r < 4; ++r) {
    const int id = wg * 4 + r;
    const int b = id >> 5, p = id & 31;
    __syncthreads();
    rb[tid] = ldcv(oF + ((size_t)p * 32 + b) * 512 + tid);
    ib[tid] = src[b * 512 + tid];
    __syncthreads();
    const int w = tid >> 6, lane = tid & 63;
    for (int s = w; s < 512; s += 8) {
      const float* er = Esrc + (size_t)ib[s] * 512;
      float acc = 0.f;
#pragma unroll
      for (int i = 0; i < 8; ++i) acc = fmaf(rb[lane * 8 + i], er[lane * 8 + i], acc);
      acc = wredsum(acc);
      if (lane == 0) sc[s] = acc * SCALE_INV;
    }
    __syncthreads();
    const float mx = blockMax(sc[tid], red, tid);
    const float e = expf(sc[tid] - mx);
    const float sum = blockSum(e, red, tid);
    out[1024 + ((size_t)b * 32 + p) * 512 + tid] = e / sum;
  }
}

template<bool BIG>
__global__ void __launch_bounds__(TPB)
s2s_mega(const int* __restrict__ src, const float* __restrict__ Esrc, const float* __restrict__ Etrg,
         const float* __restrict__ Wih, const float* __restrict__ Whh,
         const float* __restrict__ bih, const float* __restrict__ bhh,
         const float* __restrict__ Wfc, const float* __restrict__ bfc,
         const float* __restrict__ Wh2o, const float* __restrict__ bh2o,
         const float* __restrict__ bout, float* __restrict__ out,
         float* __restrict__ ws, const float* __restrict__ ET, float* __restrict__ ETw)
{
  float* SM;
  if constexpr (BIG) { extern __shared__ float SMd[]; SM = SMd; }
  else { __shared__ float SMs[16384]; SM = SMs; }
  float* SMW = SM + L_W;
  float* sc  = SM + L_SC;
  float* rb  = SM + L_RB;
  int*   ib  = (int*)(SM + L_IB);
  float* red = SM + L_RED;
  float* hidT; float* gv; int* gi; int* tokL;
  if constexpr (BIG) {
    hidT = SM + L_HID; gv = SM + L_GV; gi = (int*)(SM + L_GI); tokL = (int*)(SM + L_TOK);
  } else {
    hidT = SM; gv = SM + 13824; gi = (int*)(SM + 13952); tokL = (int*)(SM + 15360);
  }

  unsigned* sb = (unsigned*)ws;
  float* H0 = ws + OFF_H0;
  float* H1 = ws + OFF_H1;
  float* P  = ws + OFF_P;
  float* Hl = ws + OFF_HL;
  float* hD = ws + OFF_HD;
  float* oF = ws + OFF_OF;
  float* cV = ws + OFF_CV;
  int*   cI = (int*)(ws + OFF_CI);

  const int wg = blockIdx.x, tid = threadIdx.x;
  const bool useET = (ET != nullptr);
  unsigned lg = 0u;
  float c0 = 0.f, c1 = 0.f;

  // layer-1 biases for this thread's owned column (lanes kc<2 only)
  float bs1[4] = {0.f, 0.f, 0.f, 0.f};
  {
    const int kc = tid & 15;
    if (kc < 2) {
      const int d = (wg << 1) | kc;
#pragma unroll
      for (int q = 0; q < 4; ++q)
        bs1[q] = bih[2048 + q * 512 + d] + bhh[2048 + q * 512 + d];
    }
  }

  // ---- setup: zero carried H state ----
  {
    const int gid = wg * TPB + tid;
    if (gid < BD) stcv(H0 + gid, 0.f);
    else if (gid < 2 * BD) stcv(H1 + gid - BD, 0.f);
  }
  // ---- P[0] = emb([SOS]) @ Wih0^T + biases ----
  {
    const int w = tid >> 6, lane = tid & 63;
    const int q = w >> 1, dl = w & 1;
    const int j = q * 512 + wg * 2 + dl;
    const float* er = Etrg + 512;               // token 1 ([SOS])
    const float* wr = Wih + (size_t)j * 512;
    float p = 0.f;
#pragma unroll
    for (int i = 0; i < 8; ++i) p = fmaf(er[lane * 8 + i], wr[lane * 8 + i], p);
    p = wredsum(p);
    p += bih[j] + bhh[j];
    if (lane < 32) P[(size_t)lane * 2048 + j] = p;
  }
  if (ETw) transposeET(wg, tid, Etrg, ETw, SM);
  stageW(wg, tid, Wih, Whh, SMW);
  gbar(sb, lg);

  int cur0 = 0, cur1 = 0;
  for (int t = 0; t < 32; ++t) {
    if constexpr (!BIG) { if (t > 0) stageW(wg, tid, Wih, Whh, SMW); }
    for (int k = 0; k <= t + 1; ++k) {
      const bool doA = (k <= t), doB = (k >= 1);
      float* HlP = (t == 31 && doB) ? (Hl + (size_t)(k - 1) * BD) : nullptr;
      const int kp = (k < 32) ? k : 31;
      phaseAB(wg, tid, doA, doB,
              H0 + (size_t)cur0 * BD, H0 + (size_t)(cur0 ^ 1) * BD,
              H1 + (size_t)cur1 * BD, H1 + (size_t)(cur1 ^ 1) * BD,
              HlP, P + (size_t)kp * Bb * 2048, bs1, SMW, c0, c1);
      if constexpr (BIG) {
        // fold previous step's logits/argmax into the first two phases (t>=2)
        if (t >= 2 && k == 0) {
          if (useET) phaseG_ET<16>(wg, tid, hD, ET, bout, cV, cI, hidT, gv, gi);
          else       phaseG_noET(wg, tid, hD, Etrg, bout, cV, cI, rb, gv, gi);
        }
        if (t >= 2 && k == 1)
          phaseHP(wg, tid, t - 1, useET, cV, cI, Etrg, Wih, bih, bhh, P, out, tokL);
      }
      gbar(sb, lg);
      if (doA) cur0 ^= 1;
      if (doB) cur1 ^= 1;
    }
    if (wg < 32) phaseCDEF(wg, tid, H1 + (size_t)cur1 * BD, Wfc, bfc, src, Esrc,
                           Wh2o, bh2o, hD, sc, rb, ib, red);
    gbar(sb, lg);
    if constexpr (BIG) {
      if (t == 0) {     // bootstrap: G(0), HP(0) standalone (P[1] needed at t=1,k=1)
        if (useET) phaseG_ET<16>(wg, tid, hD, ET, bout, cV, cI, hidT, gv, gi);
        else       phaseG_noET(wg, tid, hD, Etrg, bout, cV, cI, rb, gv, gi);
        gbar(sb, lg);
        phaseHP(wg, tid, 0, useET, cV, cI, Etrg, Wih, bih, bhh, P, out, tokL);
        gbar(sb, lg);
      }
    } else {
      if (useET) phaseG_ET<18>(wg, tid, hD, ET, bout, cV, cI, hidT, gv, gi);
      else       phaseG_noET(wg, tid, hD, Etrg, bout, cV, cI, rb, gv, gi);
      gbar(sb, lg);
      phaseHP(wg, tid, t, useET, cV, cI, Etrg, Wih, bih, bhh, P, out, tokL);
      gbar(sb, lg);
    }
  }
  // tail: BIG still owes G(31)/HP(31); fold into X / Y phases.
  phaseX(wg, tid, Hl, Wfc, bfc, oF);
  if constexpr (BIG) {
    if (useET) phaseG_ET<16>(wg, tid, hD, ET, bout, cV, cI, hidT, gv, gi);
    else       phaseG_noET(wg, tid, hD, Etrg, bout, cV, cI, rb, gv, gi);
  }
  gbar(sb, lg);
  if constexpr (BIG)
    phaseHP(wg, tid, 31, useET, cV, cI, Etrg, Wih, bih, bhh, P, out, tokL);
  phaseY(wg, tid, oF, src, Esrc, out, sc, rb, ib, red);
}

extern "C" void kernel_launch(void* const* d_in, const int* in_sizes, int n_in,
                              void* d_out, int out_size, void* d_ws, size_t ws_size,
                              hipStream_t stream) {
  const int*   src  = (const int*)d_in[0];
  const float* Esrc = (const float*)d_in[1];
  const float* Etrg = (const float*)d_in[2];
  const float* Wih  = (const float*)d_in[3];
  const float* Whh  = (const float*)d_in[4];
  const float* bih  = (const float*)d_in[5];
  const float* bhh  = (const float*)d_in[6];
  const float* Wfc  = (const float*)d_in[7];
  const float* bfc  = (const float*)d_in[8];
  const float* Wh2o = (const float*)d_in[9];
  const float* bh2o = (const float*)d_in[10];
  const float* bout = (const float*)d_in[11];
  float* ws = (float*)d_ws;

  const size_t needET = (OFF_ET + (size_t)512 * 32000) * sizeof(float);
  const bool useET = (ws_size >= needET);
  float* etw = useET ? (ws + OFF_ET) : nullptr;

  hipMemsetAsync(d_ws, 0, 16384, stream);   // reset barrier counters + flags

  hipError_t ae = hipFuncSetAttribute(
      reinterpret_cast<const void*>(&s2s_mega<true>),
      hipFuncAttributeMaxDynamicSharedMemorySize, (int)BIG_BYTES);
  if (ae == hipSuccess) {
    s2s_mega<true><<<dim3(NWG), dim3(TPB), BIG_BYTES, stream>>>(
        src, Esrc, Etrg, Wih, Whh, bih, bhh, Wfc, bfc, Wh2o, bh2o, bout,
        (float*)d_out, ws, etw, etw);
  } else {
    s2s_mega<false><<<dim3(NWG), dim3(TPB), 0, stream>>>(
        src, Esrc, Etrg, Wih, Whh, bih, bhh, Wfc, bfc, Wh2o, bh2o, bout,
        (float*)d_out, ws, etw, etw);
  }
}

// Round 4
// 19837.901 us; speedup vs baseline: 1.3774x; 1.3774x over previous
//
#include <hip/hip_runtime.h>
#include <math.h>

#define NWG 256
#define TPB 512
#define AGT __HIP_MEMORY_SCOPE_AGENT

// ---- sizes ----
static constexpr int Bb = 32, Dd = 512, Tt = 32, Vv = 32000;
static constexpr int BD = Bb * Dd;                       // 16384
static constexpr float SCALE_INV = 0.04419417382415922f; // 1/sqrt(512)

// ---- ws layout (float offsets). Sync region = first 16 KB. ----
static constexpr size_t OFF_H0 = 4096;
static constexpr size_t OFF_H1 = OFF_H0 + 2 * (size_t)BD;
static constexpr size_t OFF_P  = OFF_H1 + 2 * (size_t)BD;             // [32][32][2048]
static constexpr size_t OFF_HL = OFF_P + (size_t)Tt * Bb * 2048;      // [32][32][512]
static constexpr size_t OFF_HD = OFF_HL + (size_t)Tt * BD;
static constexpr size_t OFF_OF = OFF_HD + BD;                          // [32][32][512]
static constexpr size_t OFF_CV = OFF_OF + (size_t)Tt * BD;             // [32][256]
static constexpr size_t OFF_CI = OFF_CV + 32 * 256;
static constexpr size_t OFF_ET = OFF_CI + 32 * 256;                    // ETb [16000][512][2]

// ---- LDS region offsets (floats), dynamic total 130,240 B ----
static constexpr int L_W   = 0;       // 24 x 576 weight rows (slant-packed)
static constexpr int L_H   = 13824;   // 16384: H stage buffer / hidT(PAD18) / ETb-build tile
static constexpr int L_SC  = 30208;   // 512
static constexpr int L_RB  = 30720;   // 1024
static constexpr int L_IB  = 31744;   // 512
static constexpr int L_RED = 32256;   // 16
static constexpr int L_GV  = 32272;   // 128
static constexpr int L_GI  = 32400;   // 128
static constexpr int L_TOK = 32528;   // 32
static constexpr int LDS_FLOATS = 32560;
static constexpr size_t LDS_BYTES = (size_t)LDS_FLOATS * 4;

__device__ __forceinline__ float sigm(float x) { return 1.0f / (1.0f + expf(-x)); }

// ---- IC-coherent (sc1) access: relaxed agent-scope atomics (bypass L2, no inv/wb) ----
__device__ __forceinline__ float ldcv(const float* p) {
  unsigned u = __hip_atomic_load((const unsigned*)p, __ATOMIC_RELAXED, AGT);
  return __builtin_bit_cast(float, u);
}
__device__ __forceinline__ void stcv(float* p, float v) {
  __hip_atomic_store((unsigned*)p, __builtin_bit_cast(unsigned, v), __ATOMIC_RELAXED, AGT);
}
__device__ __forceinline__ float2 ldcv2(const float* p) {
  unsigned long long u = __hip_atomic_load((const unsigned long long*)p, __ATOMIC_RELAXED, AGT);
  return __builtin_bit_cast(float2, u);
}
__device__ __forceinline__ int ldcvi(const int* p) {
  return (int)__hip_atomic_load((const unsigned*)p, __ATOMIC_RELAXED, AGT);
}
__device__ __forceinline__ void stcvi(int* p, int v) {
  __hip_atomic_store((unsigned*)p, (unsigned)v, __ATOMIC_RELAXED, AGT);
}

__device__ __forceinline__ float wredsum(float v) {
#pragma unroll
  for (int off = 32; off > 0; off >>= 1) v += __shfl_xor(v, off, 64);
  return v;
}

// ---- fence-free 2-level grid barrier, spread release flags ----
__device__ __forceinline__ void gbar(unsigned* sb, unsigned& lg) {
  const unsigned tgt = lg + 1u;
  asm volatile("s_waitcnt vmcnt(0)" ::: "memory");
  __syncthreads();
  if (threadIdx.x == 0) {
    const int g = (int)blockIdx.x >> 5;
    unsigned a = __hip_atomic_fetch_add(&sb[g * 64], 1u, __ATOMIC_RELAXED, AGT);
    if (a == 31u) {
      __hip_atomic_store(&sb[g * 64], 0u, __ATOMIC_RELAXED, AGT);
      unsigned r = __hip_atomic_fetch_add(&sb[1024], 1u, __ATOMIC_RELAXED, AGT);
      if (r == 7u) {
        __hip_atomic_store(&sb[1024], 0u, __ATOMIC_RELAXED, AGT);
#pragma unroll
        for (int gg = 0; gg < 8; ++gg)
          __hip_atomic_store(&sb[2048 + gg * 64], tgt, __ATOMIC_RELAXED, AGT);
      }
    }
    while (__hip_atomic_load(&sb[2048 + g * 64], __ATOMIC_RELAXED, AGT) < tgt)
      __builtin_amdgcn_s_sleep(1);
  }
  lg = tgt;
  __syncthreads();
}

__device__ __forceinline__ float blockMax(float v, float* red, int tid) {
#pragma unroll
  for (int off = 32; off > 0; off >>= 1) v = fmaxf(v, __shfl_xor(v, off, 64));
  if ((tid & 63) == 0) red[tid >> 6] = v;
  __syncthreads();
  float m = red[0];
#pragma unroll
  for (int i = 1; i < 8; ++i) m = fmaxf(m, red[i]);
  __syncthreads();
  return m;
}

__device__ __forceinline__ float blockSum(float v, float* red, int tid) {
  v = wredsum(v);
  if ((tid & 63) == 0) red[tid >> 6] = v;
  __syncthreads();
  float s = 0.f;
#pragma unroll
  for (int i = 0; i < 8; ++i) s += red[i];
  __syncthreads();
  return s;
}

// ---- stage this WG's 24 weight rows into LDS (slant-packed: chunk kc at kc*36) ----
__device__ void stageW(int wg, int tid, const float* __restrict__ Wih,
                       const float* __restrict__ Whh, float* __restrict__ SMW) {
  for (int e = tid; e < 3 * 8 * 512; e += TPB) {
    const int k = e & 511, jl = (e >> 9) & 7, m = e >> 12;
    const int q = jl >> 1, dl = jl & 1;
    const int j = q * 512 + wg * 2 + dl;
    const float* srcp = (m == 0) ? (Whh + (size_t)j * 512)
                     : (m == 1) ? (Wih + (size_t)2048 * 512 + (size_t)j * 512)
                                : (Whh + (size_t)2048 * 512 + (size_t)j * 512);
    SMW[(m * 8 + jl) * 576 + (k >> 5) * 36 + (k & 31)] = srcp[k];
  }
  __syncthreads();
}

// ---- WG-private build of ETb[v/2][k][2] from Etrg (panel [wg*128, wg*128+128)) ----
__device__ void buildETb(int wg, int tid, const float* __restrict__ Etrg,
                         float* __restrict__ ETb, float* __restrict__ SM) {
  if (wg < 250) {
    for (int tile = 0; tile < 8; ++tile) {
      const int tv = tile >> 2, tk = tile & 3;
      __syncthreads();
      for (int e = tid; e < 64 * 128; e += TPB) {
        const int vl = e >> 7, kl = e & 127;
        SM[vl * 129 + kl] = Etrg[(size_t)(wg * 128 + tv * 64 + vl) * 512 + tk * 128 + kl];
      }
      __syncthreads();
      for (int e = tid; e < 32 * 128; e += TPB) {
        const int vp = e >> 7, kl = e & 127;
        const int v = wg * 128 + tv * 64 + vp * 2;
        const int k = tk * 128 + kl;
        float2 val = make_float2(SM[(vp * 2) * 129 + kl], SM[(vp * 2 + 1) * 129 + kl]);
        *(float2*)(ETb + ((size_t)(v >> 1) * 512 + k) * 2) = val;
      }
    }
    __syncthreads();
  }
}

// ---- merged LSTM phase: A = L0(pos p), B = L1(pos p-1). tid = b*16 + kc.
// H exchanged via fully-coalesced sc1 loads -> swizzled LDS stage -> registers.
__device__ __forceinline__ void phaseAB(
    int wg, int tid, bool doA, bool doB,
    const float* __restrict__ H0r, float* __restrict__ H0w,
    const float* __restrict__ H1r, float* __restrict__ H1w,
    float* __restrict__ HlP, const float* __restrict__ Pp,
    const float* __restrict__ bs1,
    const float* __restrict__ SMW, float* __restrict__ LH, float& c0, float& c1)
{
  const int kc = tid & 15, b = tid >> 4;
  float4 s0[8], s1[8];
  __builtin_amdgcn_sched_barrier(0);
  {
    const float* p0 = H0r + tid * 4;
#pragma unroll
    for (int r = 0; r < 8; ++r) {
      const float* q = p0 + r * 2048;
      asm volatile("global_load_dwordx4 %0, %1, off sc1" : "=v"(s0[r]) : "v"(q));
    }
  }
  if (doB) {
    const float* p1 = H1r + tid * 4;
#pragma unroll
    for (int r = 0; r < 8; ++r) {
      const float* q = p1 + r * 2048;
      asm volatile("global_load_dwordx4 %0, %1, off sc1" : "=v"(s1[r]) : "v"(q));
    }
  }
  __builtin_amdgcn_sched_barrier(0);
  asm volatile("s_waitcnt vmcnt(0)" ::: "memory");
  __builtin_amdgcn_sched_barrier(0);
  // H0 -> LDS (XOR-swizzled, conflict-free both sides)
#pragma unroll
  for (int r = 0; r < 8; ++r) {
    int byte = (r * 512 + tid) * 16;
    byte ^= ((byte >> 7) & 7) << 4;
    *(float4*)((char*)LH + byte) = s0[r];
  }
  __syncthreads();
  float4 hq[8];
#pragma unroll
  for (int j = 0; j < 8; ++j) {
    int byte = tid * 128 + j * 16;
    byte ^= ((byte >> 7) & 7) << 4;
    hq[j] = *(const float4*)((const char*)LH + byte);
  }
  if (doB) {
    __syncthreads();                 // all H0 reads done; reuse LH for H1
#pragma unroll
    for (int r = 0; r < 8; ++r) {
      int byte = (r * 512 + tid) * 16;
      byte ^= ((byte >> 7) & 7) << 4;
      *(float4*)((char*)LH + byte) = s1[r];
    }
  }
  float accA[8], accB[8];
#pragma unroll
  for (int r = 0; r < 8; ++r) { accA[r] = 0.f; accB[r] = 0.f; }
  if (doA) {
#pragma unroll
    for (int r = 0; r < 8; ++r) {
      const float4* wr = (const float4*)(SMW + r * 576 + kc * 36);
#pragma unroll
      for (int iq = 0; iq < 8; ++iq) {
        float4 w = wr[iq];
        accA[r] = fmaf(w.x, hq[iq].x, accA[r]);
        accA[r] = fmaf(w.y, hq[iq].y, accA[r]);
        accA[r] = fmaf(w.z, hq[iq].z, accA[r]);
        accA[r] = fmaf(w.w, hq[iq].w, accA[r]);
      }
    }
  }
  if (doB) {
#pragma unroll
    for (int r = 0; r < 8; ++r) {       // Wih1 . H0
      const float4* wr = (const float4*)(SMW + (8 + r) * 576 + kc * 36);
#pragma unroll
      for (int iq = 0; iq < 8; ++iq) {
        float4 w = wr[iq];
        accB[r] = fmaf(w.x, hq[iq].x, accB[r]);
        accB[r] = fmaf(w.y, hq[iq].y, accB[r]);
        accB[r] = fmaf(w.z, hq[iq].z, accB[r]);
        accB[r] = fmaf(w.w, hq[iq].w, accB[r]);
      }
    }
    __syncthreads();                 // H1 visible in LH
#pragma unroll
    for (int j = 0; j < 8; ++j) {
      int byte = tid * 128 + j * 16;
      byte ^= ((byte >> 7) & 7) << 4;
      hq[j] = *(const float4*)((const char*)LH + byte);
    }
#pragma unroll
    for (int r = 0; r < 8; ++r) {       // Whh1 . H1
      const float4* wr = (const float4*)(SMW + (16 + r) * 576 + kc * 36);
#pragma unroll
      for (int iq = 0; iq < 8; ++iq) {
        float4 w = wr[iq];
        accB[r] = fmaf(w.x, hq[iq].x, accB[r]);
        accB[r] = fmaf(w.y, hq[iq].y, accB[r]);
        accB[r] = fmaf(w.z, hq[iq].z, accB[r]);
        accB[r] = fmaf(w.w, hq[iq].w, accB[r]);
      }
    }
  }
#pragma unroll
  for (int off = 1; off < 16; off <<= 1) {   // reduce over the 16 kc lanes
    if (doA) {
#pragma unroll
      for (int r = 0; r < 8; ++r) accA[r] += __shfl_xor(accA[r], off, 64);
    }
    if (doB) {
#pragma unroll
      for (int r = 0; r < 8; ++r) accB[r] += __shfl_xor(accB[r], off, 64);
    }
  }
  if (kc < 2) {                        // lanes kc=0,1 own columns d = wg*2+kc
    const int d = (wg << 1) | kc;
    if (doA) {
      const float* pb = Pp + b * 2048 + d;
      const float gi = accA[0 + kc] + pb[0];
      const float gf = accA[2 + kc] + pb[512];
      const float gg = accA[4 + kc] + pb[1024];
      const float go = accA[6 + kc] + pb[1536];
      c0 = sigm(gf) * c0 + sigm(gi) * tanhf(gg);
      stcv(H0w + b * 512 + d, sigm(go) * tanhf(c0));
    }
    if (doB) {
      const float gi = accB[0 + kc] + bs1[0];
      const float gf = accB[2 + kc] + bs1[1];
      const float gg = accB[4 + kc] + bs1[2];
      const float go = accB[6 + kc] + bs1[3];
      c1 = sigm(gf) * c1 + sigm(gi) * tanhf(gg);
      const float hn = sigm(go) * tanhf(c1);
      stcv(H1w + b * 512 + d, hn);
      if (HlP) stcv(HlP + b * 512 + d, hn);
    }
  }
}

// ---- fused fc + attention + context + h2o for one batch row (WGs 0..31) ----
__device__ void phaseCDEF(int b, int tid, const float* __restrict__ H1c,
                          const float* __restrict__ Wfc, const float* __restrict__ bfc,
                          const int* __restrict__ src, const float* __restrict__ Esrc,
                          const float* __restrict__ Wh2o, const float* __restrict__ bh2o,
                          float* __restrict__ hD, float* sc, float* rb, int* ib, float* red)
{
  rb[tid] = ldcv(H1c + b * 512 + tid);
  ib[tid] = src[b * 512 + tid];
  __syncthreads();
  const int w = tid >> 6, lane = tid & 63;
  for (int d = w; d < 512; d += 8) {            // fc_out
    const float* wr = Wfc + (size_t)d * 512;
    float p = 0.f;
#pragma unroll
    for (int i = 0; i < 8; ++i) p = fmaf(rb[lane * 8 + i], wr[lane * 8 + i], p);
    p = wredsum(p);
    if (lane == 0) rb[512 + d] = p + bfc[d];
  }
  __syncthreads();
  for (int s = w; s < 512; s += 8) {            // scores
    const float* er = Esrc + (size_t)ib[s] * 512;
    float p = 0.f;
#pragma unroll
    for (int i = 0; i < 8; ++i) p = fmaf(rb[512 + lane * 8 + i], er[lane * 8 + i], p);
    p = wredsum(p);
    if (lane == 0) sc[s] = p * SCALE_INV;
  }
  __syncthreads();
  const float mx = blockMax(sc[tid], red, tid);
  const float e = expf(sc[tid] - mx);
  sc[tid] = e;
  const float sum = blockSum(e, red, tid);
  const float inv = 1.0f / sum;
  float acc = 0.f;
#pragma unroll 4
  for (int s = 0; s < 512; ++s) acc = fmaf(sc[s], Esrc[(size_t)ib[s] * 512 + tid], acc);
  rb[tid] = acc * inv;                          // ctx into rb[0:512]
  __syncthreads();
  for (int d = w; d < 512; d += 8) {            // h2o + relu
    const float* wr = Wh2o + (size_t)d * 1024;
    float p = 0.f;
#pragma unroll
    for (int i = 0; i < 8; ++i) p = fmaf(rb[512 + lane * 8 + i], wr[lane * 8 + i], p);
#pragma unroll
    for (int i = 0; i < 8; ++i) p = fmaf(rb[lane * 8 + i], wr[512 + lane * 8 + i], p);
    p = wredsum(p);
    if (lane == 0) stcv(hD + (size_t)b * 512 + d, fmaxf(p + bh2o[d], 0.f));
  }
}

// ---- logits + per-slot argmax candidates, streaming ETb[v/2][k][2] ----
__device__ void phaseG_ET(int wg, int tid, const float* __restrict__ hD, const float* __restrict__ ETb,
                          const float* __restrict__ bout, float* __restrict__ candV,
                          int* __restrict__ candI, float* hidT, float* gv, int* gi)
{
  if (wg >= 250) return;
  const int v0 = wg * 128;
#pragma unroll 1
  for (int ph = 0; ph < 2; ++ph) {
    const int bbase = ph * 16;
    __syncthreads();
    for (int e = tid; e < 16 * 512; e += TPB) {   // hidT[k][b], PAD 18
      const int bb = e >> 9, k = e & 511;
      hidT[k * 18 + bb] = ldcv(hD + (size_t)(bbase + bb) * 512 + k);
    }
    __syncthreads();
    const int vp = tid >> 3, bh = tid & 7;
    const int v = v0 + vp * 2;
    float a00 = 0.f, a01 = 0.f, a10 = 0.f, a11 = 0.f;
    const float* ep = ETb + (size_t)(v >> 1) * 1024;
    const float* hp = hidT + bh * 2;
#pragma unroll 8
    for (int k = 0; k < 512; ++k) {
      const float2 e2 = *(const float2*)(ep + k * 2);
      const float2 h2 = *(const float2*)(hp + k * 18);
      a00 = fmaf(e2.x, h2.x, a00);
      a01 = fmaf(e2.x, h2.y, a01);
      a10 = fmaf(e2.y, h2.x, a10);
      a11 = fmaf(e2.y, h2.y, a11);
    }
    const float bo0 = bout[v], bo1 = bout[v + 1];
    a00 += bo0; a01 += bo0; a10 += bo1; a11 += bo1;
    float vA, vB; int iA, iB;
    if (a10 > a00) { vA = a10; iA = v + 1; } else { vA = a00; iA = v; }
    if (a11 > a01) { vB = a11; iB = v + 1; } else { vB = a01; iB = v; }
#pragma unroll
    for (int off = 8; off < 64; off <<= 1) {
      float ov = __shfl_xor(vA, off, 64); int oi = __shfl_xor(iA, off, 64);
      if (ov > vA || (ov == vA && oi < iA)) { vA = ov; iA = oi; }
      ov = __shfl_xor(vB, off, 64); oi = __shfl_xor(iB, off, 64);
      if (ov > vB || (ov == vB && oi < iB)) { vB = ov; iB = oi; }
    }
    if ((tid & 63) < 8) {
      const int w = tid >> 6;
      gv[(bh * 2 + 0) * 8 + w] = vA; gi[(bh * 2 + 0) * 8 + w] = iA;
      gv[(bh * 2 + 1) * 8 + w] = vB; gi[(bh * 2 + 1) * 8 + w] = iB;
    }
    __syncthreads();
    if (tid < 16) {
      float bv = -INFINITY; int bi = 0;
      for (int w2 = 0; w2 < 8; ++w2) {
        const float vv = gv[tid * 8 + w2]; const int ii = gi[tid * 8 + w2];
        if (vv > bv || (vv == bv && ii < bi)) { bv = vv; bi = ii; }
      }
      stcv(candV + (size_t)(bbase + tid) * 256 + wg, bv);
      stcvi(candI + (bbase + tid) * 256 + wg, bi);
    }
  }
}

// ---- fallback logits (row-major E), wave-per-v ----
__device__ void phaseG_noET(int wg, int tid, const float* __restrict__ hD,
                            const float* __restrict__ Etrg, const float* __restrict__ bout,
                            float* __restrict__ candV, int* __restrict__ candI,
                            float* rb, float* gv, int* gi)
{
  const int b = wg >> 3, vb = wg & 7;
  rb[tid] = ldcv(hD + (size_t)b * 512 + tid);
  __syncthreads();
  const int w = tid >> 6, lane = tid & 63;
  float bv = -INFINITY; int bi = 0;
  for (int v = vb * 4000 + w; v < (vb + 1) * 4000; v += 8) {
    const float* er = Etrg + (size_t)v * 512;
    float p = 0.f;
#pragma unroll
    for (int i = 0; i < 8; ++i) p = fmaf(rb[lane * 8 + i], er[lane * 8 + i], p);
    p = wredsum(p);
    p += bout[v];
    if (p > bv || (p == bv && v < bi)) { bv = p; bi = v; }
  }
  if (lane == 0) { gv[w] = bv; gi[w] = bi; }
  __syncthreads();
  if (tid == 0) {
    float fv = -INFINITY; int fi = 0;
    for (int w2 = 0; w2 < 8; ++w2)
      if (gv[w2] > fv || (gv[w2] == fv && gi[w2] < fi)) { fv = gv[w2]; fi = gi[w2]; }
    stcv(candV + (size_t)b * 256 + vb, fv);
    stcvi(candI + b * 256 + vb, fi);
  }
  __syncthreads();
}

// ---- token argmax finalize + P[t+1] projection ----
__device__ void phaseHP(int wg, int tid, int t, bool useET,
                        const float* __restrict__ candV, const int* __restrict__ candI,
                        const float* __restrict__ Etrg, const float* __restrict__ Wih,
                        const float* __restrict__ bih, const float* __restrict__ bhh,
                        float* __restrict__ P, float* __restrict__ out, int* tokL)
{
  const int nslot = useET ? 250 : 8;
  {
    const int b = tid >> 4, sl = tid & 15;
    float bv = -INFINITY; int bi = 0x7fffffff;
    for (int s = sl; s < nslot; s += 16) {
      const float vv = ldcv(candV + (size_t)b * 256 + s);
      const int ii = ldcvi(candI + b * 256 + s);
      if (vv > bv || (vv == bv && ii < bi)) { bv = vv; bi = ii; }
    }
#pragma unroll
    for (int off = 1; off < 16; off <<= 1) {
      const float ov = __shfl_xor(bv, off, 64); const int oi = __shfl_xor(bi, off, 64);
      if (ov > bv || (ov == bv && oi < bi)) { bv = ov; bi = oi; }
    }
    if (sl == 0) {
      tokL[b] = bi;
      if (wg == 0) out[b * 32 + t] = (float)bi;   // tokens[:,1:][b][t]
    }
  }
  __syncthreads();
  if (t < 31) {
    const int w = tid >> 6, lane = tid & 63;
    const int q = w >> 1, dl = w & 1;
    const int j = q * 512 + wg * 2 + dl;
    const float* wr = Wih + (size_t)j * 512;
    const float bsum = bih[j] + bhh[j];
    for (int b = 0; b < 32; ++b) {
      const float* er = Etrg + (size_t)tokL[b] * 512;
      float p = 0.f;
#pragma unroll
      for (int i = 0; i < 8; ++i) p = fmaf(er[lane * 8 + i], wr[lane * 8 + i], p);
      p = wredsum(p);
      if (lane == 0) P[((size_t)(t + 1) * 32 + b) * 2048 + j] = p + bsum;
    }
  }
  __syncthreads();
}

// ---- outfc[p][b][:] = Hlast[p][b] @ Wfc^T + bfc ----
__device__ void phaseX(int wg, int tid, const float* __restrict__ Hl, const float* __restrict__ Wfc,
                       const float* __restrict__ bfc, float* __restrict__ oF)
{
  const int p = wg >> 3, bq = wg & 7;
  const int w = tid >> 6, lane = tid & 63;
  for (int u = w; u < 2048; u += 8) {
    const int bb = u >> 9, d = u & 511;
    const int b = bq * 4 + bb;
    const float* hr = Hl + ((size_t)p * 32 + b) * 512;
    const float* wr = Wfc + (size_t)d * 512;
    float acc = 0.f;
#pragma unroll
    for (int ii = 0; ii < 4; ++ii) {
      const float2 hv = ldcv2(hr + lane * 8 + 2 * ii);
      acc = fmaf(hv.x, wr[lane * 8 + 2 * ii], acc);
      acc = fmaf(hv.y, wr[lane * 8 + 2 * ii + 1], acc);
    }
    acc = wredsum(acc);
    if (lane == 0) stcv(oF + ((size_t)p * 32 + b) * 512 + d, acc + bfc[d]);
  }
}

// ---- final attn rows: softmax_s(outfc[p][b] . src_e[b][s] / sqrt(D)) ----
__device__ void phaseY(int wg, int tid, const float* __restrict__ oF, const int* __restrict__ src,
                       const float* __restrict__ Esrc, float* __restrict__ out,
                       float* sc, float* rb, int* ib, float* red)
{
  for (int r = 0; r < 4; ++r) {
    const int id = wg * 4 + r;
    const int b = id >> 5, p = id & 31;
    __syncthreads();
    rb[tid] = ldcv(oF + ((size_t)p * 32 + b) * 512 + tid);
    ib[tid] = src[b * 512 + tid];
    __syncthreads();
    const int w = tid >> 6, lane = tid & 63;
    for (int s = w; s < 512; s += 8) {
      const float* er = Esrc + (size_t)ib[s] * 512;
      float acc = 0.f;
#pragma unroll
      for (int i = 0; i < 8; ++i) acc = fmaf(rb[lane * 8 + i], er[lane * 8 + i], acc);
      acc = wredsum(acc);
      if (lane == 0) sc[s] = acc * SCALE_INV;
    }
    __syncthreads();
    const float mx = blockMax(sc[tid], red, tid);
    const float e = expf(sc[tid] - mx);
    const float sum = blockSum(e, red, tid);
    out[1024 + ((size_t)b * 32 + p) * 512 + tid] = e / sum;
  }
}

extern "C" __global__ void __launch_bounds__(TPB)
s2s_mega(const int* __restrict__ src, const float* __restrict__ Esrc, const float* __restrict__ Etrg,
         const float* __restrict__ Wih, const float* __restrict__ Whh,
         const float* __restrict__ bih, const float* __restrict__ bhh,
         const float* __restrict__ Wfc, const float* __restrict__ bfc,
         const float* __restrict__ Wh2o, const float* __restrict__ bh2o,
         const float* __restrict__ bout, float* __restrict__ out,
         float* __restrict__ ws, const float* __restrict__ ET, float* __restrict__ ETw)
{
  extern __shared__ float SM[];
  float* SMW = SM + L_W;
  float* LH  = SM + L_H;       // H stage / hidT / ETb-build tile
  float* sc  = SM + L_SC;
  float* rb  = SM + L_RB;
  int*   ib  = (int*)(SM + L_IB);
  float* red = SM + L_RED;
  float* gv  = SM + L_GV;
  int*   gi  = (int*)(SM + L_GI);
  int*   tokL = (int*)(SM + L_TOK);

  unsigned* sb = (unsigned*)ws;
  float* H0 = ws + OFF_H0;
  float* H1 = ws + OFF_H1;
  float* P  = ws + OFF_P;
  float* Hl = ws + OFF_HL;
  float* hD = ws + OFF_HD;
  float* oF = ws + OFF_OF;
  float* cV = ws + OFF_CV;
  int*   cI = (int*)(ws + OFF_CI);

  const int wg = blockIdx.x, tid = threadIdx.x;
  const bool useET = (ET != nullptr);
  unsigned lg = 0u;
  float c0 = 0.f, c1 = 0.f;

  // layer-1 biases for this thread's owned column (lanes kc<2 only)
  float bs1[4] = {0.f, 0.f, 0.f, 0.f};
  {
    const int kc = tid & 15;
    if (kc < 2) {
      const int d = (wg << 1) | kc;
#pragma unroll
      for (int q = 0; q < 4; ++q)
        bs1[q] = bih[2048 + q * 512 + d] + bhh[2048 + q * 512 + d];
    }
  }

  // ---- setup: zero carried H state ----
  {
    const int gid = wg * TPB + tid;
    if (gid < BD) stcv(H0 + gid, 0.f);
    else if (gid < 2 * BD) stcv(H1 + gid - BD, 0.f);
  }
  // ---- P[0] = emb([SOS]) @ Wih0^T + biases ----
  {
    const int w = tid >> 6, lane = tid & 63;
    const int q = w >> 1, dl = w & 1;
    const int j = q * 512 + wg * 2 + dl;
    const float* er = Etrg + 512;               // token 1 ([SOS])
    const float* wr = Wih + (size_t)j * 512;
    float p = 0.f;
#pragma unroll
    for (int i = 0; i < 8; ++i) p = fmaf(er[lane * 8 + i], wr[lane * 8 + i], p);
    p = wredsum(p);
    p += bih[j] + bhh[j];
    if (lane < 32) P[(size_t)lane * 2048 + j] = p;
  }
  if (ETw) buildETb(wg, tid, Etrg, ETw, LH);
  stageW(wg, tid, Wih, Whh, SMW);
  gbar(sb, lg);

  int cur0 = 0, cur1 = 0;
  for (int t = 0; t < 32; ++t) {
    for (int k = 0; k <= t + 1; ++k) {
      const bool doA = (k <= t), doB = (k >= 1);
      float* HlP = (t == 31 && doB) ? (Hl + (size_t)(k - 1) * BD) : nullptr;
      const int kp = (k < 32) ? k : 31;
      phaseAB(wg, tid, doA, doB,
              H0 + (size_t)cur0 * BD, H0 + (size_t)(cur0 ^ 1) * BD,
              H1 + (size_t)cur1 * BD, H1 + (size_t)(cur1 ^ 1) * BD,
              HlP, P + (size_t)kp * Bb * 2048, bs1, SMW, LH, c0, c1);
      // fold previous step's logits/argmax into the first two phases (t>=2)
      if (t >= 2 && k == 0) {
        if (useET) phaseG_ET(wg, tid, hD, ET, bout, cV, cI, LH, gv, gi);
        else       phaseG_noET(wg, tid, hD, Etrg, bout, cV, cI, rb, gv, gi);
      }
      if (t >= 2 && k == 1)
        phaseHP(wg, tid, t - 1, useET, cV, cI, Etrg, Wih, bih, bhh, P, out, tokL);
      gbar(sb, lg);
      if (doA) cur0 ^= 1;
      if (doB) cur1 ^= 1;
    }
    if (wg < 32) phaseCDEF(wg, tid, H1 + (size_t)cur1 * BD, Wfc, bfc, src, Esrc,
                           Wh2o, bh2o, hD, sc, rb, ib, red);
    gbar(sb, lg);
    if (t == 0) {     // bootstrap: G(0), HP(0) standalone (P[1] needed at t=1,k=1)
      if (useET) phaseG_ET(wg, tid, hD, ET, bout, cV, cI, LH, gv, gi);
      else       phaseG_noET(wg, tid, hD, Etrg, bout, cV, cI, rb, gv, gi);
      gbar(sb, lg);
      phaseHP(wg, tid, 0, useET, cV, cI, Etrg, Wih, bih, bhh, P, out, tokL);
      gbar(sb, lg);
    }
  }
  // tail: G(31)/HP(31) folded into X / Y phases.
  phaseX(wg, tid, Hl, Wfc, bfc, oF);
  if (useET) phaseG_ET(wg, tid, hD, ET, bout, cV, cI, LH, gv, gi);
  else       phaseG_noET(wg, tid, hD, Etrg, bout, cV, cI, rb, gv, gi);
  gbar(sb, lg);
  phaseHP(wg, tid, 31, useET, cV, cI, Etrg, Wih, bih, bhh, P, out, tokL);
  phaseY(wg, tid, oF, src, Esrc, out, sc, rb, ib, red);
}

extern "C" void kernel_launch(void* const* d_in, const int* in_sizes, int n_in,
                              void* d_out, int out_size, void* d_ws, size_t ws_size,
                              hipStream_t stream) {
  const int*   src  = (const int*)d_in[0];
  const float* Esrc = (const float*)d_in[1];
  const float* Etrg = (const float*)d_in[2];
  const float* Wih  = (const float*)d_in[3];
  const float* Whh  = (const float*)d_in[4];
  const float* bih  = (const float*)d_in[5];
  const float* bhh  = (const float*)d_in[6];
  const float* Wfc  = (const float*)d_in[7];
  const float* bfc  = (const float*)d_in[8];
  const float* Wh2o = (const float*)d_in[9];
  const float* bh2o = (const float*)d_in[10];
  const float* bout = (const float*)d_in[11];
  float* ws = (float*)d_ws;

  const size_t needET = (OFF_ET + (size_t)512 * 32000) * sizeof(float);
  const bool useET = (ws_size >= needET);
  float* etw = useET ? (ws + OFF_ET) : nullptr;

  hipMemsetAsync(d_ws, 0, 16384, stream);   // reset barrier counters + flags

  static bool attrDone = false;
  hipFuncSetAttribute(reinterpret_cast<const void*>(&s2s_mega),
                      hipFuncAttributeMaxDynamicSharedMemorySize, (int)LDS_BYTES);

  s2s_mega<<<dim3(NWG), dim3(TPB), LDS_BYTES, stream>>>(
      src, Esrc, Etrg, Wih, Whh, bih, bhh, Wfc, bfc, Wh2o, bh2o, bout,
      (float*)d_out, ws, etw, etw);
}